// Round 19
// baseline (1402.291 us; speedup 1.0000x reference)
//
#include <hip/hip_runtime.h>
#include <math.h>

#define R_ROWS 49152      // B*N*S = 128*32*12
#define HID 1024
#define SLOT 256
#define EMB 256
#define ACT 128
#define NCODE 1024
#define M_ROWS 47616      // B*(N-1)*S = 128*31*12

// output offsets (float elements)
#define OFF_AD 0
#define OFF_Z  12189696
#define OFF_AV 18284544
#define OFF_QS 24379392
#define OFF_IDX 30474240
#define OFF_QL 30521856
#define OFF_CL 30521857

// workspace offsets (float elements)
#define WS_XH    0
#define WS_XL    6291456
#define WS_MT   12582912
#define WS_VT   18874368
#define WS_W1H  25165824
#define WS_W1L  25296896
#define WS_W2H  25427968
#define WS_W2L  25559040
#define WS_WMH  25690112
#define WS_WML  25706496
#define WS_WVH  25722880
#define WS_WVL  25739264
#define WS_CBH  25755648
#define WS_CBL  25821184
#define WS_CN   25886720
#define WS_V0   25887744
#define WS_V1   25888000
#define WS_LOSS 25888256

typedef _Float16 f16x8 __attribute__((ext_vector_type(8)));
typedef float f32x4 __attribute__((ext_vector_type(4)));

// ---------------- fused pack kernel ----------------
__device__ __forceinline__ void pack_body(
    const float* __restrict__ W, _Float16* __restrict__ hi, _Float16* __restrict__ lo,
    int lgS, int N, int p, const float* __restrict__ scale)
{
    int j = p & 7;
    int l = (p >> 3) & 63;
    int q = p >> 9;
    int s = q & ((1 << lgS) - 1);
    int t = q >> lgS;
    int n = t * 16 + (l & 15);
    int k = s * 32 + ((l >> 4) << 3) + j;
    float x = W[(size_t)k * N + n];
    if (scale) x *= scale[k];
    _Float16 h = (_Float16)x;
    hi[p] = h;
    lo[p] = (_Float16)(x - (float)h);
}

__global__ __launch_bounds__(256) void k_packall(
    const float* __restrict__ W1, const float* __restrict__ W2,
    const float* __restrict__ Wm, const float* __restrict__ Wv,
    const float* __restrict__ CB, const float* __restrict__ X,
    const float* __restrict__ ln_g, const float* __restrict__ ln_b,
    const float* __restrict__ b2,
    _Float16* __restrict__ W1h, _Float16* __restrict__ W1l,
    _Float16* __restrict__ W2h, _Float16* __restrict__ W2l,
    _Float16* __restrict__ Wmh, _Float16* __restrict__ Wml,
    _Float16* __restrict__ Wvh, _Float16* __restrict__ Wvl,
    _Float16* __restrict__ CBh, _Float16* __restrict__ CBl,
    _Float16* __restrict__ Xh, _Float16* __restrict__ Xl,
    float* __restrict__ cn, float* __restrict__ v0, float* __restrict__ v1,
    float* __restrict__ losss)
{
    const int bi = blockIdx.x;
    const int tid = threadIdx.x;
    if (bi == 0 && tid == 0) *losss = 0.f;

    if (bi < 1024) {
        pack_body(W1, W1h, W1l, 3, HID, bi * 256 + tid, (const float*)0);
    } else if (bi < 2048) {
        pack_body(W2, W2h, W2l, 5, EMB, (bi - 1024) * 256 + tid, ln_g);
    } else if (bi < 2176) {
        pack_body(Wm, Wmh, Wml, 3, ACT, (bi - 2048) * 256 + tid, (const float*)0);
    } else if (bi < 2304) {
        pack_body(Wv, Wvh, Wvl, 3, ACT, (bi - 2176) * 256 + tid, (const float*)0);
    } else if (bi < 2816) {
        int p = (bi - 2304) * 256 + tid;
        int j = p & 7;
        int l = (p >> 3) & 63;
        int q = p >> 9;
        int s = q & 7;
        int t = q >> 3;
        int n = t * 32 + (l & 31);
        int k = s * 16 + ((l >> 5) << 3) + j;
        float x = CB[(size_t)n * ACT + k];
        _Float16 h = (_Float16)x;
        CBh[p] = h;
        CBl[p] = (_Float16)(x - (float)h);
    } else if (bi < 2820) {
        int c = (bi - 2816) * 256 + tid;
        float s = 0.f;
        #pragma unroll
        for (int k = 0; k < ACT; k += 4) {
            float4 v = *(const float4*)&CB[(size_t)c * ACT + k];
            s += v.x*v.x + v.y*v.y + v.z*v.z + v.w*v.w;
        }
        cn[c] = s;
    } else if (bi < 8964) {
        size_t e0 = ((size_t)(bi - 2820) * 256 + tid) * 8;
        float4 va = *(const float4*)&X[e0];
        float4 vb = *(const float4*)&X[e0 + 4];
        float xv[8] = {va.x, va.y, va.z, va.w, vb.x, vb.y, vb.z, vb.w};
        f16x8 h8, l8;
        #pragma unroll
        for (int e = 0; e < 8; ++e) {
            _Float16 h = (_Float16)xv[e];
            h8[e] = h;
            l8[e] = (_Float16)(xv[e] - (float)h);
        }
        *(f16x8*)&Xh[e0] = h8;
        *(f16x8*)&Xl[e0] = l8;
    } else {
        int n = tid;
        float a0 = 0.f, a1 = 0.f;
        for (int c = 0; c < HID; ++c) {
            float w2 = W2[(size_t)c * EMB + n];
            a1 = fmaf(ln_g[c], w2, a1);
            a0 = fmaf(ln_b[c], w2, a0);
        }
        v1[n] = a1;
        v0[n] = a0 + b2[n];
    }
}

// ---- encoder: 1024 thr / 16 waves, 64 rows/block, 4 k-panels (256 cols), LN-fold ----
// Per-wave state: acc2[4]=16 + sum/sq=32 + acc1[4]=16 + a0/a1=8 + bh/bl=8 ≈ 80 named.
__global__ __launch_bounds__(1024, 2) void k_encoder_mfma(
    const _Float16* __restrict__ Xh, const _Float16* __restrict__ Xl,
    const float* __restrict__ b1,
    const float* __restrict__ v0, const float* __restrict__ v1,
    const float* __restrict__ bm, const float* __restrict__ bv,
    const _Float16* __restrict__ W1h, const _Float16* __restrict__ W1l,
    const _Float16* __restrict__ W2h, const _Float16* __restrict__ W2l,
    const _Float16* __restrict__ Wmh, const _Float16* __restrict__ Wml,
    const _Float16* __restrict__ Wvh, const _Float16* __restrict__ Wvl,
    float* __restrict__ MT, float* __restrict__ VT)
{
    __shared__ _Float16 Ph0[64][256];    // 32 KB raw-H panel hi
    __shared__ _Float16 Ph1[64][256];    // 32 KB raw-H panel lo
    __shared__ _Float16 Es0[32][256];    // 16 KB E-half hi
    __shared__ _Float16 Es1[32][256];    // 16 KB E-half lo
    __shared__ float stat_s[2048];       // [0..1023]=sum (w*64+row), [1024..2047]=sq
    __shared__ float mu_s[64], rs_s[64];

    const int tid = threadIdx.x;
    const int w  = tid >> 6;      // 0..15
    const int l  = tid & 63;
    const int lr = l & 15;
    const int lg = l >> 4;
    const long rowbase = (long)blockIdx.x * 64;

    float sum[4][4], sq[4][4];
    #pragma unroll
    for (int rq = 0; rq < 4; ++rq)
        #pragma unroll
        for (int r = 0; r < 4; ++r) { sum[rq][r] = 0.f; sq[rq][r] = 0.f; }

    f32x4 acc2[4];   // E-tile w, 4 row-quarters; persistent; static idx only
    #pragma unroll
    for (int rq = 0; rq < 4; ++rq) acc2[rq] = (f32x4){0.f, 0.f, 0.f, 0.f};

    for (int kp = 0; kp < 4; ++kp) {
        // ---- GEMM1: wave w owns H col-tile tg1 = kp*16 + w ----
        const int tg1 = kp * 16 + w;
        f32x4 acc1[4];
        #pragma unroll
        for (int rq = 0; rq < 4; ++rq) acc1[rq] = (f32x4){0.f, 0.f, 0.f, 0.f};

        #pragma unroll
        for (int s = 0; s < 8; ++s) {
            f16x8 bh = *(const f16x8*)(W1h + ((size_t)(tg1 * 8 + s) * 64 + l) * 8);
            f16x8 bl = *(const f16x8*)(W1l + ((size_t)(tg1 * 8 + s) * 64 + l) * 8);
            #pragma unroll
            for (int rq = 0; rq < 4; ++rq) {
                size_t xoff = (size_t)(rowbase + rq * 16 + lr) * SLOT + s * 32 + lg * 8;
                f16x8 a0 = *(const f16x8*)&Xh[xoff];
                f16x8 a1 = *(const f16x8*)&Xl[xoff];
                acc1[rq] = __builtin_amdgcn_mfma_f32_16x16x32_f16(a0, bh, acc1[rq], 0, 0, 0);
                acc1[rq] = __builtin_amdgcn_mfma_f32_16x16x32_f16(a0, bl, acc1[rq], 0, 0, 0);
                acc1[rq] = __builtin_amdgcn_mfma_f32_16x16x32_f16(a1, bh, acc1[rq], 0, 0, 0);
            }
        }

        // bias + relu + stats accumulate
        {
            float bb = b1[tg1 * 16 + lr];
            #pragma unroll
            for (int rq = 0; rq < 4; ++rq)
                #pragma unroll
                for (int r = 0; r < 4; ++r) {
                    float v = fmaxf(acc1[rq][r] + bb, 0.f);
                    acc1[rq][r] = v;
                    sum[rq][r] += v;
                    sq[rq][r] = fmaf(v, v, sq[rq][r]);
                }
        }

        __syncthreads();   // previous panel's GEMM2 reads complete

        // write raw-H panel: panel-local col = w*16+lr (256 cols, 32 granules)
        {
            int np = w * 16 + lr;
            int gw = np >> 3, jj = np & 7;
            #pragma unroll
            for (int rq = 0; rq < 4; ++rq) {
                #pragma unroll
                for (int r = 0; r < 4; ++r) {
                    int row = rq * 16 + 4 * lg + r;
                    float v = acc1[rq][r];
                    _Float16 h = (_Float16)v;
                    int cs = gw ^ (row & 7);
                    Ph0[row][cs * 8 + jj] = h;
                    Ph1[row][cs * 8 + jj] = (_Float16)(v - (float)h);
                }
            }
        }
        __syncthreads();   // panel visible

        // ---- GEMM2 partial: wave w owns E-tile w; k = panel's 256 cols ----
        #pragma unroll
        for (int sl = 0; sl < 8; ++sl) {
            f16x8 bh = *(const f16x8*)(W2h + ((size_t)(w * 32 + kp * 8 + sl) * 64 + l) * 8);
            f16x8 bl = *(const f16x8*)(W2l + ((size_t)(w * 32 + kp * 8 + sl) * 64 + l) * 8);
            #pragma unroll
            for (int rq = 0; rq < 4; ++rq) {
                int row = rq * 16 + lr;
                int cs = (sl * 4 + lg) ^ (row & 7);
                f16x8 ah = *(const f16x8*)&Ph0[row][cs * 8];
                f16x8 al = *(const f16x8*)&Ph1[row][cs * 8];
                acc2[rq] = __builtin_amdgcn_mfma_f32_16x16x32_f16(ah, bh, acc2[rq], 0, 0, 0);
                acc2[rq] = __builtin_amdgcn_mfma_f32_16x16x32_f16(ah, bl, acc2[rq], 0, 0, 0);
                acc2[rq] = __builtin_amdgcn_mfma_f32_16x16x32_f16(al, bh, acc2[rq], 0, 0, 0);
            }
        }
    }

    // ---- LN stats reduce ----
    #pragma unroll
    for (int off = 1; off < 16; off <<= 1)
        #pragma unroll
        for (int rq = 0; rq < 4; ++rq)
            #pragma unroll
            for (int r = 0; r < 4; ++r) {
                sum[rq][r] += __shfl_xor(sum[rq][r], off, 64);
                sq[rq][r]  += __shfl_xor(sq[rq][r],  off, 64);
            }
    if (lr == 0) {
        #pragma unroll
        for (int rq = 0; rq < 4; ++rq)
            #pragma unroll
            for (int r = 0; r < 4; ++r) {
                int row = rq * 16 + 4 * lg + r;
                stat_s[w * 64 + row]        = sum[rq][r];
                stat_s[1024 + w * 64 + row] = sq[rq][r];
            }
    }
    __syncthreads();
    if (tid < 64) {
        float s = 0.f, q = 0.f;
        #pragma unroll
        for (int wv = 0; wv < 16; ++wv) {
            s += stat_s[wv * 64 + tid];
            q += stat_s[1024 + wv * 64 + tid];
        }
        float mu = s * (1.f / HID);
        float var = q * (1.f / HID) - mu * mu;
        mu_s[tid] = mu;
        rs_s[tid] = 1.f / sqrtf(var + 1e-5f);
    }

    // ---- E + heads: two row-half passes, HH static ----
#define ENC_HALF(HH)                                                                       \
    {                                                                                      \
        __syncthreads();                                                                   \
        {                                                                                  \
            int n = w * 16 + lr;                                                           \
            float v0r = v0[n], v1r = v1[n];                                                \
            int gw = n >> 3, jj = n & 7;                                                   \
            _Pragma("unroll")                                                              \
            for (int rql = 0; rql < 2; ++rql) {                                            \
                _Pragma("unroll")                                                          \
                for (int r = 0; r < 4; ++r) {                                              \
                    int grow = (HH * 2 + rql) * 16 + 4 * lg + r;                           \
                    int lrow = rql * 16 + 4 * lg + r;                                      \
                    float mu = mu_s[grow], rs = rs_s[grow];                                \
                    float e = rs * acc2[HH * 2 + rql][r] - rs * mu * v1r + v0r;            \
                    _Float16 h = (_Float16)e;                                              \
                    int cs = gw ^ (lrow & 7);                                              \
                    Es0[lrow][cs * 8 + jj] = h;                                            \
                    Es1[lrow][cs * 8 + jj] = (_Float16)(e - (float)h);                     \
                }                                                                          \
            }                                                                              \
        }                                                                                  \
        __syncthreads();                                                                   \
        const int half = w >> 3;                                                           \
        const int ct = w & 7;                                                              \
        const _Float16* WXh = half ? Wvh : Wmh;                                            \
        const _Float16* WXl = half ? Wvl : Wml;                                            \
        f32x4 acc3[2];                                                                     \
        _Pragma("unroll")                                                                  \
        for (int rh = 0; rh < 2; ++rh) acc3[rh] = (f32x4){0.f, 0.f, 0.f, 0.f};             \
        _Pragma("unroll")                                                                  \
        for (int s = 0; s < 8; ++s) {                                                      \
            f16x8 bh = *(const f16x8*)(WXh + ((size_t)(ct * 8 + s) * 64 + l) * 8);         \
            f16x8 bl = *(const f16x8*)(WXl + ((size_t)(ct * 8 + s) * 64 + l) * 8);         \
            _Pragma("unroll")                                                              \
            for (int rh = 0; rh < 2; ++rh) {                                               \
                int row = rh * 16 + lr;                                                    \
                int cs = (s * 4 + lg) ^ (row & 7);                                         \
                f16x8 ah = *(const f16x8*)&Es0[row][cs * 8];                               \
                f16x8 al = *(const f16x8*)&Es1[row][cs * 8];                               \
                acc3[rh] = __builtin_amdgcn_mfma_f32_16x16x32_f16(ah, bh, acc3[rh], 0, 0, 0); \
                acc3[rh] = __builtin_amdgcn_mfma_f32_16x16x32_f16(ah, bl, acc3[rh], 0, 0, 0); \
                acc3[rh] = __builtin_amdgcn_mfma_f32_16x16x32_f16(al, bh, acc3[rh], 0, 0, 0); \
            }                                                                              \
        }                                                                                  \
        {                                                                                  \
            int a = ct * 16 + lr;                                                          \
            float bx = half ? bv[a] : bm[a];                                               \
            _Pragma("unroll")                                                              \
            for (int rh = 0; rh < 2; ++rh) {                                               \
                _Pragma("unroll")                                                          \
                for (int r = 0; r < 4; ++r) {                                              \
                    float v = acc3[rh][r] + bx;                                            \
                    size_t row = rowbase + HH * 32 + rh * 16 + 4 * lg + r;                 \
                    if (half) VT[row * ACT + a] = fabsf(v);                                \
                    else      MT[row * ACT + a] = v;                                       \
                }                                                                          \
            }                                                                              \
        }                                                                                  \
    }

    ENC_HALF(0)
    ENC_HALF(1)
#undef ENC_HALF
}

// ---------------- fused action + VQ + finalize (R13/R5 exact) ----------------
__global__ __launch_bounds__(256, 2) void k_vqfused(
    const float* __restrict__ MT, const float* __restrict__ VT,
    const float* __restrict__ noise,
    const _Float16* __restrict__ CBh, const _Float16* __restrict__ CBl,
    const float* __restrict__ cn, const float* __restrict__ CB,
    float* __restrict__ out, float* __restrict__ losss)
{
    typedef float f32x16 __attribute__((ext_vector_type(16)));
    __shared__ float4 Zs4[4096];
    __shared__ int   idx_s[128];
    __shared__ float red[4];
    float* Zs = (float*)Zs4;

    const int tid = threadIdx.x;
    const int rowbase = blockIdx.x * 128;
    const int a = tid & 127;
    const int rhalf = tid >> 7;

    #pragma unroll 8
    for (int i = 0; i < 64; ++i) {
        int row = 2 * i + rhalf;
        int m = rowbase + row;
        int b = m / 372;
        int r1 = m + 12 * b;
        int r2 = r1 + 12;
        float m1 = MT[(size_t)r1 * ACT + a], m2 = MT[(size_t)r2 * ACT + a];
        float v1 = VT[(size_t)r1 * ACT + a], v2 = VT[(size_t)r2 * ACT + a];
        float adm = m2 - m1;
        float adv = v2 + v1;
        float z = noise[(size_t)m * ACT + a] * sqrtf(adv + 1e-6f) + adm;
        int np = m / 12, s = m - np * 12;
        out[OFF_AD + (size_t)(np * 24 + s) * ACT + a] = adm;
        out[OFF_AD + (size_t)(np * 24 + 12 + s) * ACT + a] = adv;
        out[OFF_Z + (size_t)m * ACT + a] = z;
        Zs[row * 128 + (((a >> 2) ^ (row & 31)) << 2) + (a & 3)] = z;
    }
    __syncthreads();

    const int w = tid >> 6, l = tid & 63;
    const int col = l & 31, hw = l >> 5;
    const int arow = 32 * w + col;

    f16x8 a0[8], a1[8];
    #pragma unroll
    for (int s = 0; s < 8; ++s) {
        #pragma unroll
        for (int half = 0; half < 2; ++half) {
            int k4 = s * 4 + hw * 2 + half;
            float4 v = *(const float4*)&Zs[arow * 128 + ((k4 ^ (arow & 31)) << 2)];
            float xv[4] = {v.x, v.y, v.z, v.w};
            #pragma unroll
            for (int e = 0; e < 4; ++e) {
                _Float16 h = (_Float16)xv[e];
                a0[s][half * 4 + e] = h;
                a1[s][half * 4 + e] = (_Float16)(xv[e] - (float)h);
            }
        }
    }

    float best[16];
    int bidx[16];
    #pragma unroll
    for (int r = 0; r < 16; ++r) { best[r] = 3.4e38f; bidx[r] = 0; }

    for (int cb = 0; cb < 4; ++cb) {
        f32x16 acc[8];
        #pragma unroll
        for (int t = 0; t < 8; ++t)
            #pragma unroll
            for (int r = 0; r < 16; ++r) acc[t][r] = 0.f;

        #pragma unroll
        for (int s = 0; s < 8; ++s) {
            #pragma unroll
            for (int t = 0; t < 8; ++t) {
                int tg = cb * 8 + t;
                f16x8 bh = *(const f16x8*)(CBh + ((size_t)(tg * 8 + s) * 64 + l) * 8);
                f16x8 bl = *(const f16x8*)(CBl + ((size_t)(tg * 8 + s) * 64 + l) * 8);
                acc[t] = __builtin_amdgcn_mfma_f32_32x32x16_f16(a0[s], bh, acc[t], 0, 0, 0);
                acc[t] = __builtin_amdgcn_mfma_f32_32x32x16_f16(a0[s], bl, acc[t], 0, 0, 0);
                acc[t] = __builtin_amdgcn_mfma_f32_32x32x16_f16(a1[s], bh, acc[t], 0, 0, 0);
            }
        }

        float cnv[8];
        #pragma unroll
        for (int t = 0; t < 8; ++t) cnv[t] = cn[cb * 256 + t * 32 + col];

        #pragma unroll
        for (int reg = 0; reg < 16; ++reg) {
            #pragma unroll
            for (int t = 0; t < 8; ++t) {
                float d = cnv[t] - 2.f * acc[t][reg];
                int gi = cb * 256 + t * 32 + col;
                if (d < best[reg]) { best[reg] = d; bidx[reg] = gi; }
            }
        }
    }

    #pragma unroll
    for (int reg = 0; reg < 16; ++reg) {
        float bv_ = best[reg];
        int bi_ = bidx[reg];
        #pragma unroll
        for (int off = 1; off < 32; off <<= 1) {
            float ov = __shfl_xor(bv_, off, 64);
            int   oi = __shfl_xor(bi_, off, 64);
            if (ov < bv_ || (ov == bv_ && oi < bi_)) { bv_ = ov; bi_ = oi; }
        }
        if (col == 0) {
            int mloc = 32 * w + (reg & 3) + 8 * (reg >> 2) + 4 * hw;
            idx_s[mloc] = bi_;
            out[OFF_IDX + rowbase + mloc] = (float)bi_;
        }
    }
    __syncthreads();

    float ls = 0.f;
    #pragma unroll 8
    for (int i = 0; i < 64; ++i) {
        int row = 2 * i + rhalf;
        float z = Zs[row * 128 + (((a >> 2) ^ (row & 31)) << 2) + (a & 3)];
        int ci = idx_s[row];
        float q = CB[(size_t)ci * ACT + a];
        float diff = z - q;
        size_t m = (size_t)(rowbase + row);
        out[OFF_QS + m * ACT + a] = z + (q - z);
        out[OFF_AV + m * ACT + a] = diff;
        ls = fmaf(diff, diff, ls);
    }
    #pragma unroll
    for (int off = 32; off; off >>= 1) ls += __shfl_xor(ls, off, 64);
    if (l == 0) red[w] = ls;
    __syncthreads();
    if (tid == 0) atomicAdd(losss, red[0] + red[1] + red[2] + red[3]);
}

__global__ void k_losses(const float* __restrict__ losss, float* __restrict__ out)
{
    float v = *losss * (1.f / 6094848.f);
    out[OFF_QL] = v;
    out[OFF_CL] = v;
}

extern "C" void kernel_launch(void* const* d_in, const int* in_sizes, int n_in,
                              void* d_out, int out_size, void* d_ws, size_t ws_size,
                              hipStream_t stream)
{
    const float* slots = (const float*)d_in[0];
    const float* noise = (const float*)d_in[1];
    const float* W1    = (const float*)d_in[2];
    const float* b1    = (const float*)d_in[3];
    const float* ln_g  = (const float*)d_in[4];
    const float* ln_b  = (const float*)d_in[5];
    const float* W2    = (const float*)d_in[6];
    const float* b2    = (const float*)d_in[7];
    const float* Wm    = (const float*)d_in[8];
    const float* bm    = (const float*)d_in[9];
    const float* Wv    = (const float*)d_in[10];
    const float* bv    = (const float*)d_in[11];
    const float* CB    = (const float*)d_in[12];
    float* out = (float*)d_out;
    float* ws  = (float*)d_ws;

    float* MT    = ws + WS_MT;
    float* VT    = ws + WS_VT;
    float* cn    = ws + WS_CN;
    float* v0    = ws + WS_V0;
    float* v1    = ws + WS_V1;
    float* losss = ws + WS_LOSS;

    _Float16* Xh  = (_Float16*)(ws + WS_XH);
    _Float16* Xl  = (_Float16*)(ws + WS_XL);
    _Float16* W1h = (_Float16*)(ws + WS_W1H);
    _Float16* W1l = (_Float16*)(ws + WS_W1L);
    _Float16* W2h = (_Float16*)(ws + WS_W2H);
    _Float16* W2l = (_Float16*)(ws + WS_W2L);
    _Float16* Wmh = (_Float16*)(ws + WS_WMH);
    _Float16* Wml = (_Float16*)(ws + WS_WML);
    _Float16* Wvh = (_Float16*)(ws + WS_WVH);
    _Float16* Wvl = (_Float16*)(ws + WS_WVL);
    _Float16* CBh = (_Float16*)(ws + WS_CBH);
    _Float16* CBl = (_Float16*)(ws + WS_CBL);

    hipLaunchKernelGGL(k_packall, dim3(8965), dim3(256), 0, stream,
                       W1, W2, Wm, Wv, CB, slots, ln_g, ln_b, b2,
                       W1h, W1l, W2h, W2l, Wmh, Wml, Wvh, Wvl, CBh, CBl,
                       Xh, Xl, cn, v0, v1, losss);
    hipLaunchKernelGGL(k_encoder_mfma, dim3(R_ROWS/64), dim3(1024), 0, stream,
                       Xh, Xl, b1, v0, v1, bm, bv,
                       W1h, W1l, W2h, W2l, Wmh, Wml, Wvh, Wvl, MT, VT);
    hipLaunchKernelGGL(k_vqfused, dim3(M_ROWS/128), dim3(256), 0, stream,
                       MT, VT, noise, CBh, CBl, cn, CB, out, losss);
    hipLaunchKernelGGL(k_losses, dim3(1), dim3(1), 0, stream, losss, out);
}

// Round 20
// 1091.338 us; speedup vs baseline: 1.2849x; 1.2849x over previous
//
#include <hip/hip_runtime.h>
#include <math.h>

#define R_ROWS 49152      // B*N*S = 128*32*12
#define HID 1024
#define SLOT 256
#define EMB 256
#define ACT 128
#define NCODE 1024
#define M_ROWS 47616      // B*(N-1)*S = 128*31*12

// output offsets (float elements)
#define OFF_AD 0
#define OFF_Z  12189696
#define OFF_AV 18284544
#define OFF_QS 24379392
#define OFF_IDX 30474240
#define OFF_QL 30521856
#define OFF_CL 30521857

// workspace offsets (float elements)
#define WS_XH    0
#define WS_XL    6291456
#define WS_MT   12582912
#define WS_VT   18874368
#define WS_W1H  25165824
#define WS_W1L  25296896
#define WS_W2H  25427968
#define WS_W2L  25559040
#define WS_WMH  25690112
#define WS_WML  25706496
#define WS_WVH  25722880
#define WS_WVL  25739264
#define WS_CBH  25755648
#define WS_CBL  25821184
#define WS_CN   25886720
#define WS_V0   25887744
#define WS_V1   25888000
#define WS_LOSS 25888256

typedef _Float16 f16x8 __attribute__((ext_vector_type(8)));
typedef float f32x4 __attribute__((ext_vector_type(4)));

// ---------------- fused pack kernel ----------------
__device__ __forceinline__ void pack_body(
    const float* __restrict__ W, _Float16* __restrict__ hi, _Float16* __restrict__ lo,
    int lgS, int N, int p, const float* __restrict__ scale)
{
    int j = p & 7;
    int l = (p >> 3) & 63;
    int q = p >> 9;
    int s = q & ((1 << lgS) - 1);
    int t = q >> lgS;
    int n = t * 16 + (l & 15);
    int k = s * 32 + ((l >> 4) << 3) + j;
    float x = W[(size_t)k * N + n];
    if (scale) x *= scale[k];
    _Float16 h = (_Float16)x;
    hi[p] = h;
    lo[p] = (_Float16)(x - (float)h);
}

__global__ __launch_bounds__(256) void k_packall(
    const float* __restrict__ W1, const float* __restrict__ W2,
    const float* __restrict__ Wm, const float* __restrict__ Wv,
    const float* __restrict__ CB, const float* __restrict__ X,
    const float* __restrict__ ln_g, const float* __restrict__ ln_b,
    const float* __restrict__ b2,
    _Float16* __restrict__ W1h, _Float16* __restrict__ W1l,
    _Float16* __restrict__ W2h, _Float16* __restrict__ W2l,
    _Float16* __restrict__ Wmh, _Float16* __restrict__ Wml,
    _Float16* __restrict__ Wvh, _Float16* __restrict__ Wvl,
    _Float16* __restrict__ CBh, _Float16* __restrict__ CBl,
    _Float16* __restrict__ Xh, _Float16* __restrict__ Xl,
    float* __restrict__ cn, float* __restrict__ v0, float* __restrict__ v1,
    float* __restrict__ losss)
{
    const int bi = blockIdx.x;
    const int tid = threadIdx.x;
    if (bi == 0 && tid == 0) *losss = 0.f;

    if (bi < 1024) {
        pack_body(W1, W1h, W1l, 3, HID, bi * 256 + tid, (const float*)0);
    } else if (bi < 2048) {
        pack_body(W2, W2h, W2l, 5, EMB, (bi - 1024) * 256 + tid, ln_g);
    } else if (bi < 2176) {
        pack_body(Wm, Wmh, Wml, 3, ACT, (bi - 2048) * 256 + tid, (const float*)0);
    } else if (bi < 2304) {
        pack_body(Wv, Wvh, Wvl, 3, ACT, (bi - 2176) * 256 + tid, (const float*)0);
    } else if (bi < 2816) {
        int p = (bi - 2304) * 256 + tid;
        int j = p & 7;
        int l = (p >> 3) & 63;
        int q = p >> 9;
        int s = q & 7;
        int t = q >> 3;
        int n = t * 32 + (l & 31);
        int k = s * 16 + ((l >> 5) << 3) + j;
        float x = CB[(size_t)n * ACT + k];
        _Float16 h = (_Float16)x;
        CBh[p] = h;
        CBl[p] = (_Float16)(x - (float)h);
    } else if (bi < 2820) {
        int c = (bi - 2816) * 256 + tid;
        float s = 0.f;
        #pragma unroll
        for (int k = 0; k < ACT; k += 4) {
            float4 v = *(const float4*)&CB[(size_t)c * ACT + k];
            s += v.x*v.x + v.y*v.y + v.z*v.z + v.w*v.w;
        }
        cn[c] = s;
    } else if (bi < 8964) {
        size_t e0 = ((size_t)(bi - 2820) * 256 + tid) * 8;
        float4 va = *(const float4*)&X[e0];
        float4 vb = *(const float4*)&X[e0 + 4];
        float xv[8] = {va.x, va.y, va.z, va.w, vb.x, vb.y, vb.z, vb.w};
        f16x8 h8, l8;
        #pragma unroll
        for (int e = 0; e < 8; ++e) {
            _Float16 h = (_Float16)xv[e];
            h8[e] = h;
            l8[e] = (_Float16)(xv[e] - (float)h);
        }
        *(f16x8*)&Xh[e0] = h8;
        *(f16x8*)&Xl[e0] = l8;
    } else {
        int n = tid;
        float a0 = 0.f, a1 = 0.f;
        for (int c = 0; c < HID; ++c) {
            float w2 = W2[(size_t)c * EMB + n];
            a1 = fmaf(ln_g[c], w2, a1);
            a0 = fmaf(ln_b[c], w2, a0);
        }
        v1[n] = a1;
        v0[n] = a0 + b2[n];
    }
}

// ---- encoder: 512 thr / 8 waves, 64 rows/block, 8 k-panels, LN-fold ----
// (512,2): VGPR cap 128 (cap = 256/max(N, T/256)). Live state cut: LN stats
// accumulate in LDS (not persistent VGPRs); single a-frag per rq in GEMM1.
__global__ __launch_bounds__(512, 2) void k_encoder_mfma(
    const _Float16* __restrict__ Xh, const _Float16* __restrict__ Xl,
    const float* __restrict__ b1,
    const float* __restrict__ v0, const float* __restrict__ v1,
    const float* __restrict__ bm, const float* __restrict__ bv,
    const _Float16* __restrict__ W1h, const _Float16* __restrict__ W1l,
    const _Float16* __restrict__ W2h, const _Float16* __restrict__ W2l,
    const _Float16* __restrict__ Wmh, const _Float16* __restrict__ Wml,
    const _Float16* __restrict__ Wvh, const _Float16* __restrict__ Wvl,
    float* __restrict__ MT, float* __restrict__ VT)
{
    __shared__ _Float16 Ph0[64][128];    // 16 KB raw-H panel hi
    __shared__ _Float16 Ph1[64][128];    // 16 KB raw-H panel lo
    __shared__ _Float16 Es0[32][256];    // 16 KB E-half hi
    __shared__ _Float16 Es1[32][256];    // 16 KB E-half lo
    __shared__ float stat_s[1024];       // [0..511]=sum (w*64+row), [512..1023]=sq
    __shared__ float mu_s[64], rs_s[64];

    const int tid = threadIdx.x;
    const int w  = tid >> 6;      // 0..7
    const int l  = tid & 63;
    const int lr = l & 15;
    const int lg = l >> 4;
    const long rowbase = (long)blockIdx.x * 64;

    // zero the per-wave stat accumulators
    stat_s[tid] = 0.f;
    stat_s[512 + tid] = 0.f;
    __syncthreads();

    f32x4 acc2[2][4];   // [te][rq], persistent across panels; static idx only
    #pragma unroll
    for (int t = 0; t < 2; ++t)
        #pragma unroll
        for (int rq = 0; rq < 4; ++rq) acc2[t][rq] = (f32x4){0.f, 0.f, 0.f, 0.f};

    for (int kp = 0; kp < 8; ++kp) {
        const int tg1 = kp * 8 + w;
        f32x4 acc1[4];
        #pragma unroll
        for (int rq = 0; rq < 4; ++rq) acc1[rq] = (f32x4){0.f, 0.f, 0.f, 0.f};

        #pragma unroll
        for (int s = 0; s < 8; ++s) {
            f16x8 bh = *(const f16x8*)(W1h + ((size_t)(tg1 * 8 + s) * 64 + l) * 8);
            f16x8 bl = *(const f16x8*)(W1l + ((size_t)(tg1 * 8 + s) * 64 + l) * 8);
            #pragma unroll
            for (int rq = 0; rq < 4; ++rq) {
                size_t xoff = (size_t)(rowbase + rq * 16 + lr) * SLOT + s * 32 + lg * 8;
                f16x8 a0 = *(const f16x8*)&Xh[xoff];
                f16x8 a1 = *(const f16x8*)&Xl[xoff];
                acc1[rq] = __builtin_amdgcn_mfma_f32_16x16x32_f16(a0, bh, acc1[rq], 0, 0, 0);
                acc1[rq] = __builtin_amdgcn_mfma_f32_16x16x32_f16(a0, bl, acc1[rq], 0, 0, 0);
                acc1[rq] = __builtin_amdgcn_mfma_f32_16x16x32_f16(a1, bh, acc1[rq], 0, 0, 0);
            }
        }

        // bias + relu, then per-panel stats -> LDS accumulate (transient regs)
        {
            float bb = b1[tg1 * 16 + lr];
            float sum[4][4], sq[4][4];
            #pragma unroll
            for (int rq = 0; rq < 4; ++rq)
                #pragma unroll
                for (int r = 0; r < 4; ++r) {
                    float v = fmaxf(acc1[rq][r] + bb, 0.f);
                    acc1[rq][r] = v;
                    sum[rq][r] = v;
                    sq[rq][r] = v * v;
                }
            #pragma unroll
            for (int off = 1; off < 16; off <<= 1)
                #pragma unroll
                for (int rq = 0; rq < 4; ++rq)
                    #pragma unroll
                    for (int r = 0; r < 4; ++r) {
                        sum[rq][r] += __shfl_xor(sum[rq][r], off, 64);
                        sq[rq][r]  += __shfl_xor(sq[rq][r],  off, 64);
                    }
            if (lr == 0) {
                #pragma unroll
                for (int rq = 0; rq < 4; ++rq)
                    #pragma unroll
                    for (int r = 0; r < 4; ++r) {
                        int row = rq * 16 + 4 * lg + r;
                        stat_s[w * 64 + row]       += sum[rq][r];
                        stat_s[512 + w * 64 + row] += sq[rq][r];
                    }
            }
        }

        __syncthreads();   // previous panel's GEMM2 reads complete

        {
            int np = w * 16 + lr;
            int gw = np >> 3, jj = np & 7;
            #pragma unroll
            for (int rq = 0; rq < 4; ++rq) {
                #pragma unroll
                for (int r = 0; r < 4; ++r) {
                    int row = rq * 16 + 4 * lg + r;
                    float v = acc1[rq][r];
                    _Float16 h = (_Float16)v;
                    int cs = gw ^ (row & 7);
                    Ph0[row][cs * 8 + jj] = h;
                    Ph1[row][cs * 8 + jj] = (_Float16)(v - (float)h);
                }
            }
        }
        __syncthreads();   // panel visible

        #pragma unroll
        for (int sl = 0; sl < 4; ++sl) {
            f16x8 bh[2], bl[2];
            #pragma unroll
            for (int t = 0; t < 2; ++t) {
                size_t o = ((size_t)((w * 2 + t) * 32 + kp * 4 + sl) * 64 + l) * 8;
                bh[t] = *(const f16x8*)&W2h[o];
                bl[t] = *(const f16x8*)&W2l[o];
            }
            #pragma unroll
            for (int rq = 0; rq < 4; ++rq) {
                int row = rq * 16 + lr;
                int cs = (sl * 4 + lg) ^ (row & 7);
                f16x8 ah = *(const f16x8*)&Ph0[row][cs * 8];
                f16x8 al = *(const f16x8*)&Ph1[row][cs * 8];
                #pragma unroll
                for (int t = 0; t < 2; ++t) {
                    acc2[t][rq] = __builtin_amdgcn_mfma_f32_16x16x32_f16(ah, bh[t], acc2[t][rq], 0, 0, 0);
                    acc2[t][rq] = __builtin_amdgcn_mfma_f32_16x16x32_f16(ah, bl[t], acc2[t][rq], 0, 0, 0);
                    acc2[t][rq] = __builtin_amdgcn_mfma_f32_16x16x32_f16(al, bh[t], acc2[t][rq], 0, 0, 0);
                }
            }
        }
    }

    // ---- LN final reduce across waves (stats already summed over panels) ----
    __syncthreads();
    if (tid < 64) {
        float s = 0.f, q = 0.f;
        #pragma unroll
        for (int wv = 0; wv < 8; ++wv) {
            s += stat_s[wv * 64 + tid];
            q += stat_s[512 + wv * 64 + tid];
        }
        float mu = s * (1.f / HID);
        float var = q * (1.f / HID) - mu * mu;
        mu_s[tid] = mu;
        rs_s[tid] = 1.f / sqrtf(var + 1e-5f);
    }

    // ---- E + heads: two row-half passes, HH static ----
#define ENC_HALF(HH)                                                                       \
    {                                                                                      \
        __syncthreads();                                                                   \
        _Pragma("unroll")                                                                  \
        for (int t = 0; t < 2; ++t) {                                                      \
            int n = (w * 2 + t) * 16 + lr;                                                 \
            float v0r = v0[n], v1r = v1[n];                                                \
            int gw = n >> 3, jj = n & 7;                                                   \
            _Pragma("unroll")                                                              \
            for (int rql = 0; rql < 2; ++rql) {                                            \
                _Pragma("unroll")                                                          \
                for (int r = 0; r < 4; ++r) {                                              \
                    int grow = (HH * 2 + rql) * 16 + 4 * lg + r;                           \
                    int lrow = rql * 16 + 4 * lg + r;                                      \
                    float mu = mu_s[grow], rs = rs_s[grow];                                \
                    float e = rs * acc2[t][HH * 2 + rql][r] - rs * mu * v1r + v0r;         \
                    _Float16 h = (_Float16)e;                                              \
                    int cs = gw ^ (lrow & 7);                                              \
                    Es0[lrow][cs * 8 + jj] = h;                                            \
                    Es1[lrow][cs * 8 + jj] = (_Float16)(e - (float)h);                     \
                }                                                                          \
            }                                                                              \
        }                                                                                  \
        __syncthreads();                                                                   \
        const int half = w >> 2;                                                           \
        const int cb4 = w & 3;                                                             \
        const _Float16* WXh = half ? Wvh : Wmh;                                            \
        const _Float16* WXl = half ? Wvl : Wml;                                            \
        f32x4 acc3[2][2];                                                                  \
        _Pragma("unroll")                                                                  \
        for (int t = 0; t < 2; ++t)                                                        \
            _Pragma("unroll")                                                              \
            for (int rh = 0; rh < 2; ++rh) acc3[t][rh] = (f32x4){0.f, 0.f, 0.f, 0.f};      \
        _Pragma("unroll")                                                                  \
        for (int s = 0; s < 8; ++s) {                                                      \
            f16x8 bh[2], bl[2];                                                            \
            _Pragma("unroll")                                                              \
            for (int t = 0; t < 2; ++t) {                                                  \
                size_t o = ((size_t)((cb4 * 2 + t) * 8 + s) * 64 + l) * 8;                 \
                bh[t] = *(const f16x8*)&WXh[o];                                            \
                bl[t] = *(const f16x8*)&WXl[o];                                            \
            }                                                                              \
            _Pragma("unroll")                                                              \
            for (int rh = 0; rh < 2; ++rh) {                                               \
                int row = rh * 16 + lr;                                                    \
                int cs = (s * 4 + lg) ^ (row & 7);                                         \
                f16x8 ah = *(const f16x8*)&Es0[row][cs * 8];                               \
                f16x8 al = *(const f16x8*)&Es1[row][cs * 8];                               \
                _Pragma("unroll")                                                          \
                for (int t = 0; t < 2; ++t) {                                              \
                    acc3[t][rh] = __builtin_amdgcn_mfma_f32_16x16x32_f16(ah, bh[t], acc3[t][rh], 0, 0, 0); \
                    acc3[t][rh] = __builtin_amdgcn_mfma_f32_16x16x32_f16(ah, bl[t], acc3[t][rh], 0, 0, 0); \
                    acc3[t][rh] = __builtin_amdgcn_mfma_f32_16x16x32_f16(al, bh[t], acc3[t][rh], 0, 0, 0); \
                }                                                                          \
            }                                                                              \
        }                                                                                  \
        _Pragma("unroll")                                                                  \
        for (int t = 0; t < 2; ++t) {                                                      \
            int a = (cb4 * 2 + t) * 16 + lr;                                               \
            float bx = half ? bv[a] : bm[a];                                               \
            _Pragma("unroll")                                                              \
            for (int rh = 0; rh < 2; ++rh) {                                               \
                _Pragma("unroll")                                                          \
                for (int r = 0; r < 4; ++r) {                                              \
                    float v = acc3[t][rh][r] + bx;                                         \
                    size_t row = rowbase + HH * 32 + rh * 16 + 4 * lg + r;                 \
                    if (half) VT[row * ACT + a] = fabsf(v);                                \
                    else      MT[row * ACT + a] = v;                                       \
                }                                                                          \
            }                                                                              \
        }                                                                                  \
    }

    ENC_HALF(0)
    ENC_HALF(1)
#undef ENC_HALF
}

// ---------------- fused action + VQ + finalize (R13/R5 exact) ----------------
__global__ __launch_bounds__(256, 2) void k_vqfused(
    const float* __restrict__ MT, const float* __restrict__ VT,
    const float* __restrict__ noise,
    const _Float16* __restrict__ CBh, const _Float16* __restrict__ CBl,
    const float* __restrict__ cn, const float* __restrict__ CB,
    float* __restrict__ out, float* __restrict__ losss)
{
    typedef float f32x16 __attribute__((ext_vector_type(16)));
    __shared__ float4 Zs4[4096];
    __shared__ int   idx_s[128];
    __shared__ float red[4];
    float* Zs = (float*)Zs4;

    const int tid = threadIdx.x;
    const int rowbase = blockIdx.x * 128;
    const int a = tid & 127;
    const int rhalf = tid >> 7;

    #pragma unroll 8
    for (int i = 0; i < 64; ++i) {
        int row = 2 * i + rhalf;
        int m = rowbase + row;
        int b = m / 372;
        int r1 = m + 12 * b;
        int r2 = r1 + 12;
        float m1 = MT[(size_t)r1 * ACT + a], m2 = MT[(size_t)r2 * ACT + a];
        float v1 = VT[(size_t)r1 * ACT + a], v2 = VT[(size_t)r2 * ACT + a];
        float adm = m2 - m1;
        float adv = v2 + v1;
        float z = noise[(size_t)m * ACT + a] * sqrtf(adv + 1e-6f) + adm;
        int np = m / 12, s = m - np * 12;
        out[OFF_AD + (size_t)(np * 24 + s) * ACT + a] = adm;
        out[OFF_AD + (size_t)(np * 24 + 12 + s) * ACT + a] = adv;
        out[OFF_Z + (size_t)m * ACT + a] = z;
        Zs[row * 128 + (((a >> 2) ^ (row & 31)) << 2) + (a & 3)] = z;
    }
    __syncthreads();

    const int w = tid >> 6, l = tid & 63;
    const int col = l & 31, hw = l >> 5;
    const int arow = 32 * w + col;

    f16x8 a0[8], a1[8];
    #pragma unroll
    for (int s = 0; s < 8; ++s) {
        #pragma unroll
        for (int half = 0; half < 2; ++half) {
            int k4 = s * 4 + hw * 2 + half;
            float4 v = *(const float4*)&Zs[arow * 128 + ((k4 ^ (arow & 31)) << 2)];
            float xv[4] = {v.x, v.y, v.z, v.w};
            #pragma unroll
            for (int e = 0; e < 4; ++e) {
                _Float16 h = (_Float16)xv[e];
                a0[s][half * 4 + e] = h;
                a1[s][half * 4 + e] = (_Float16)(xv[e] - (float)h);
            }
        }
    }

    float best[16];
    int bidx[16];
    #pragma unroll
    for (int r = 0; r < 16; ++r) { best[r] = 3.4e38f; bidx[r] = 0; }

    for (int cb = 0; cb < 4; ++cb) {
        f32x16 acc[8];
        #pragma unroll
        for (int t = 0; t < 8; ++t)
            #pragma unroll
            for (int r = 0; r < 16; ++r) acc[t][r] = 0.f;

        #pragma unroll
        for (int s = 0; s < 8; ++s) {
            #pragma unroll
            for (int t = 0; t < 8; ++t) {
                int tg = cb * 8 + t;
                f16x8 bh = *(const f16x8*)(CBh + ((size_t)(tg * 8 + s) * 64 + l) * 8);
                f16x8 bl = *(const f16x8*)(CBl + ((size_t)(tg * 8 + s) * 64 + l) * 8);
                acc[t] = __builtin_amdgcn_mfma_f32_32x32x16_f16(a0[s], bh, acc[t], 0, 0, 0);
                acc[t] = __builtin_amdgcn_mfma_f32_32x32x16_f16(a0[s], bl, acc[t], 0, 0, 0);
                acc[t] = __builtin_amdgcn_mfma_f32_32x32x16_f16(a1[s], bh, acc[t], 0, 0, 0);
            }
        }

        float cnv[8];
        #pragma unroll
        for (int t = 0; t < 8; ++t) cnv[t] = cn[cb * 256 + t * 32 + col];

        #pragma unroll
        for (int reg = 0; reg < 16; ++reg) {
            #pragma unroll
            for (int t = 0; t < 8; ++t) {
                float d = cnv[t] - 2.f * acc[t][reg];
                int gi = cb * 256 + t * 32 + col;
                if (d < best[reg]) { best[reg] = d; bidx[reg] = gi; }
            }
        }
    }

    #pragma unroll
    for (int reg = 0; reg < 16; ++reg) {
        float bv_ = best[reg];
        int bi_ = bidx[reg];
        #pragma unroll
        for (int off = 1; off < 32; off <<= 1) {
            float ov = __shfl_xor(bv_, off, 64);
            int   oi = __shfl_xor(bi_, off, 64);
            if (ov < bv_ || (ov == bv_ && oi < bi_)) { bv_ = ov; bi_ = oi; }
        }
        if (col == 0) {
            int mloc = 32 * w + (reg & 3) + 8 * (reg >> 2) + 4 * hw;
            idx_s[mloc] = bi_;
            out[OFF_IDX + rowbase + mloc] = (float)bi_;
        }
    }
    __syncthreads();

    float ls = 0.f;
    #pragma unroll 8
    for (int i = 0; i < 64; ++i) {
        int row = 2 * i + rhalf;
        float z = Zs[row * 128 + (((a >> 2) ^ (row & 31)) << 2) + (a & 3)];
        int ci = idx_s[row];
        float q = CB[(size_t)ci * ACT + a];
        float diff = z - q;
        size_t m = (size_t)(rowbase + row);
        out[OFF_QS + m * ACT + a] = z + (q - z);
        out[OFF_AV + m * ACT + a] = diff;
        ls = fmaf(diff, diff, ls);
    }
    #pragma unroll
    for (int off = 32; off; off >>= 1) ls += __shfl_xor(ls, off, 64);
    if (l == 0) red[w] = ls;
    __syncthreads();
    if (tid == 0) atomicAdd(losss, red[0] + red[1] + red[2] + red[3]);
}

__global__ void k_losses(const float* __restrict__ losss, float* __restrict__ out)
{
    float v = *losss * (1.f / 6094848.f);
    out[OFF_QL] = v;
    out[OFF_CL] = v;
}

extern "C" void kernel_launch(void* const* d_in, const int* in_sizes, int n_in,
                              void* d_out, int out_size, void* d_ws, size_t ws_size,
                              hipStream_t stream)
{
    const float* slots = (const float*)d_in[0];
    const float* noise = (const float*)d_in[1];
    const float* W1    = (const float*)d_in[2];
    const float* b1    = (const float*)d_in[3];
    const float* ln_g  = (const float*)d_in[4];
    const float* ln_b  = (const float*)d_in[5];
    const float* W2    = (const float*)d_in[6];
    const float* b2    = (const float*)d_in[7];
    const float* Wm    = (const float*)d_in[8];
    const float* bm    = (const float*)d_in[9];
    const float* Wv    = (const float*)d_in[10];
    const float* bv    = (const float*)d_in[11];
    const float* CB    = (const float*)d_in[12];
    float* out = (float*)d_out;
    float* ws  = (float*)d_ws;

    float* MT    = ws + WS_MT;
    float* VT    = ws + WS_VT;
    float* cn    = ws + WS_CN;
    float* v0    = ws + WS_V0;
    float* v1    = ws + WS_V1;
    float* losss = ws + WS_LOSS;

    _Float16* Xh  = (_Float16*)(ws + WS_XH);
    _Float16* Xl  = (_Float16*)(ws + WS_XL);
    _Float16* W1h = (_Float16*)(ws + WS_W1H);
    _Float16* W1l = (_Float16*)(ws + WS_W1L);
    _Float16* W2h = (_Float16*)(ws + WS_W2H);
    _Float16* W2l = (_Float16*)(ws + WS_W2L);
    _Float16* Wmh = (_Float16*)(ws + WS_WMH);
    _Float16* Wml = (_Float16*)(ws + WS_WML);
    _Float16* Wvh = (_Float16*)(ws + WS_WVH);
    _Float16* Wvl = (_Float16*)(ws + WS_WVL);
    _Float16* CBh = (_Float16*)(ws + WS_CBH);
    _Float16* CBl = (_Float16*)(ws + WS_CBL);

    hipLaunchKernelGGL(k_packall, dim3(8965), dim3(256), 0, stream,
                       W1, W2, Wm, Wv, CB, slots, ln_g, ln_b, b2,
                       W1h, W1l, W2h, W2l, Wmh, Wml, Wvh, Wvl, CBh, CBl,
                       Xh, Xl, cn, v0, v1, losss);
    hipLaunchKernelGGL(k_encoder_mfma, dim3(R_ROWS/64), dim3(512), 0, stream,
                       Xh, Xl, b1, v0, v1, bm, bv,
                       W1h, W1l, W2h, W2l, Wmh, Wml, Wvh, Wvl, MT, VT);
    hipLaunchKernelGGL(k_vqfused, dim3(M_ROWS/128), dim3(256), 0, stream,
                       MT, VT, noise, CBh, CBl, cn, CB, out, losss);
    hipLaunchKernelGGL(k_losses, dim3(1), dim3(1), 0, stream, losss, out);
}

// Round 21
// 403.015 us; speedup vs baseline: 3.4795x; 2.7079x over previous
//
#include <hip/hip_runtime.h>
#include <math.h>

#define R_ROWS 49152      // B*N*S = 128*32*12
#define HID 1024
#define SLOT 256
#define EMB 256
#define ACT 128
#define NCODE 1024
#define M_ROWS 47616      // B*(N-1)*S = 128*31*12

// output offsets (float elements)
#define OFF_AD 0
#define OFF_Z  12189696
#define OFF_AV 18284544
#define OFF_QS 24379392
#define OFF_IDX 30474240
#define OFF_QL 30521856
#define OFF_CL 30521857

// workspace offsets (float elements) — total ~25.9M floats = 103.6 MB
#define WS_XH    0
#define WS_XL    6291456
#define WS_MT   12582912
#define WS_VT   18874368
#define WS_W1H  25165824
#define WS_W1L  25296896
#define WS_W2H  25427968
#define WS_W2L  25559040
#define WS_WMH  25690112
#define WS_WML  25706496
#define WS_WVH  25722880
#define WS_WVL  25739264
#define WS_CBH  25755648
#define WS_CBL  25821184
#define WS_CN   25886720
#define WS_LOSS 25887744

typedef _Float16 f16x8 __attribute__((ext_vector_type(8)));
typedef float f32x4 __attribute__((ext_vector_type(4)));

// ---------------- fused pack kernel (R13 exact) ----------------
__device__ __forceinline__ void pack_body(
    const float* __restrict__ W, _Float16* __restrict__ hi, _Float16* __restrict__ lo,
    int lgS, int N, int p)
{
    int j = p & 7;
    int l = (p >> 3) & 63;
    int q = p >> 9;
    int s = q & ((1 << lgS) - 1);
    int t = q >> lgS;
    int n = t * 16 + (l & 15);
    int k = s * 32 + ((l >> 4) << 3) + j;
    float x = W[(size_t)k * N + n];
    _Float16 h = (_Float16)x;
    hi[p] = h;
    lo[p] = (_Float16)(x - (float)h);
}

__global__ __launch_bounds__(256) void k_packall(
    const float* __restrict__ W1, const float* __restrict__ W2,
    const float* __restrict__ Wm, const float* __restrict__ Wv,
    const float* __restrict__ CB, const float* __restrict__ X,
    _Float16* __restrict__ W1h, _Float16* __restrict__ W1l,
    _Float16* __restrict__ W2h, _Float16* __restrict__ W2l,
    _Float16* __restrict__ Wmh, _Float16* __restrict__ Wml,
    _Float16* __restrict__ Wvh, _Float16* __restrict__ Wvl,
    _Float16* __restrict__ CBh, _Float16* __restrict__ CBl,
    _Float16* __restrict__ Xh, _Float16* __restrict__ Xl,
    float* __restrict__ cn, float* __restrict__ losss)
{
    const int bi = blockIdx.x;
    const int tid = threadIdx.x;
    if (bi == 0 && tid == 0) *losss = 0.f;

    if (bi < 1024) {
        pack_body(W1, W1h, W1l, 3, HID, bi * 256 + tid);
    } else if (bi < 2048) {
        pack_body(W2, W2h, W2l, 5, EMB, (bi - 1024) * 256 + tid);
    } else if (bi < 2176) {
        pack_body(Wm, Wmh, Wml, 3, ACT, (bi - 2048) * 256 + tid);
    } else if (bi < 2304) {
        pack_body(Wv, Wvh, Wvl, 3, ACT, (bi - 2176) * 256 + tid);
    } else if (bi < 2816) {
        int p = (bi - 2304) * 256 + tid;
        int j = p & 7;
        int l = (p >> 3) & 63;
        int q = p >> 9;
        int s = q & 7;
        int t = q >> 3;
        int n = t * 32 + (l & 31);
        int k = s * 16 + ((l >> 5) << 3) + j;
        float x = CB[(size_t)n * ACT + k];
        _Float16 h = (_Float16)x;
        CBh[p] = h;
        CBl[p] = (_Float16)(x - (float)h);
    } else if (bi < 2820) {
        int c = (bi - 2816) * 256 + tid;
        float s = 0.f;
        #pragma unroll
        for (int k = 0; k < ACT; k += 4) {
            float4 v = *(const float4*)&CB[(size_t)c * ACT + k];
            s += v.x*v.x + v.y*v.y + v.z*v.z + v.w*v.w;
        }
        cn[c] = s;
    } else {
        size_t e0 = ((size_t)(bi - 2820) * 256 + tid) * 8;
        float4 va = *(const float4*)&X[e0];
        float4 vb = *(const float4*)&X[e0 + 4];
        float xv[8] = {va.x, va.y, va.z, va.w, vb.x, vb.y, vb.z, vb.w};
        f16x8 h8, l8;
        #pragma unroll
        for (int e = 0; e < 8; ++e) {
            _Float16 h = (_Float16)xv[e];
            h8[e] = h;
            l8[e] = (_Float16)(xv[e] - (float)h);
        }
        *(f16x8*)&Xh[e0] = h8;
        *(f16x8*)&Xl[e0] = l8;
    }
}

// ---------------- encoder: 1024 threads / 16 waves, 32 rows/block (R14 exact) ----
__global__ __launch_bounds__(1024, 4) void k_encoder_mfma(
    const _Float16* __restrict__ Xh, const _Float16* __restrict__ Xl,
    const float* __restrict__ b1, const float* __restrict__ ln_g, const float* __restrict__ ln_b,
    const float* __restrict__ b2, const float* __restrict__ bm, const float* __restrict__ bv,
    const _Float16* __restrict__ W1h, const _Float16* __restrict__ W1l,
    const _Float16* __restrict__ W2h, const _Float16* __restrict__ W2l,
    const _Float16* __restrict__ Wmh, const _Float16* __restrict__ Wml,
    const _Float16* __restrict__ Wvh, const _Float16* __restrict__ Wvl,
    float* __restrict__ MT, float* __restrict__ VT)
{
    __shared__ _Float16 Hh0[32][1024];   // 64 KB (hi); E tile aliases here
    __shared__ _Float16 Hh1[32][1024];   // 64 KB (lo)
    __shared__ float stat_s[1024];       // [0..511]=sum by (w,row), [512..1023]=sq
    __shared__ float mu_s[32], rs_s[32];

    const int tid = threadIdx.x;
    const int w  = tid >> 6;      // 0..15
    const int l  = tid & 63;
    const int lr = l & 15;
    const int lg = l >> 4;
    const long rowbase = (long)blockIdx.x * 32;

    // ---- GEMM1: wave w owns H col-tiles tg = 4w..4w+3; both 16-row halves ----
    f32x4 acc1[2][4];
    #pragma unroll
    for (int rt = 0; rt < 2; ++rt)
        #pragma unroll
        for (int t = 0; t < 4; ++t) acc1[rt][t] = (f32x4){0.f, 0.f, 0.f, 0.f};

    #pragma unroll
    for (int s = 0; s < 8; ++s) {
        f16x8 a0[2], a1[2];
        #pragma unroll
        for (int rt = 0; rt < 2; ++rt) {
            size_t xoff = (size_t)(rowbase + rt * 16 + lr) * SLOT + s * 32 + lg * 8;
            a0[rt] = *(const f16x8*)&Xh[xoff];
            a1[rt] = *(const f16x8*)&Xl[xoff];
        }
        #pragma unroll
        for (int t = 0; t < 4; ++t) {
            int tg = w * 4 + t;
            f16x8 bh = *(const f16x8*)(W1h + ((size_t)(tg * 8 + s) * 64 + l) * 8);
            f16x8 bl = *(const f16x8*)(W1l + ((size_t)(tg * 8 + s) * 64 + l) * 8);
            #pragma unroll
            for (int rt = 0; rt < 2; ++rt) {
                acc1[rt][t] = __builtin_amdgcn_mfma_f32_16x16x32_f16(a0[rt], bh, acc1[rt][t], 0, 0, 0);
                acc1[rt][t] = __builtin_amdgcn_mfma_f32_16x16x32_f16(a0[rt], bl, acc1[rt][t], 0, 0, 0);
                acc1[rt][t] = __builtin_amdgcn_mfma_f32_16x16x32_f16(a1[rt], bh, acc1[rt][t], 0, 0, 0);
            }
        }
    }

    // bias + ReLU
    #pragma unroll
    for (int rt = 0; rt < 2; ++rt)
        #pragma unroll
        for (int t = 0; t < 4; ++t) {
            float bb = b1[(w * 4 + t) * 16 + lr];
            #pragma unroll
            for (int r = 0; r < 4; ++r) acc1[rt][t][r] = fmaxf(acc1[rt][t][r] + bb, 0.f);
        }

    // LN partial stats (per wave over its 64 cols), per row-half
    #pragma unroll
    for (int rt = 0; rt < 2; ++rt) {
        float sum[4] = {0,0,0,0}, sq[4] = {0,0,0,0};
        #pragma unroll
        for (int t = 0; t < 4; ++t)
            #pragma unroll
            for (int r = 0; r < 4; ++r) {
                float v = acc1[rt][t][r];
                sum[r] += v; sq[r] = fmaf(v, v, sq[r]);
            }
        #pragma unroll
        for (int off = 1; off < 16; off <<= 1)
            #pragma unroll
            for (int r = 0; r < 4; ++r) {
                sum[r] += __shfl_xor(sum[r], off, 64);
                sq[r]  += __shfl_xor(sq[r],  off, 64);
            }
        if (lr == 0) {
            #pragma unroll
            for (int r = 0; r < 4; ++r) {
                int row = rt * 16 + 4 * lg + r;
                stat_s[w * 32 + row]       = sum[r];
                stat_s[512 + w * 32 + row] = sq[r];
            }
        }
    }
    __syncthreads();

    if (tid < 32) {
        float s = 0.f, q = 0.f;
        #pragma unroll
        for (int wv = 0; wv < 16; ++wv) {
            s += stat_s[wv * 32 + tid];
            q += stat_s[512 + wv * 32 + tid];
        }
        float mu = s * (1.f / HID);
        float var = q * (1.f / HID) - mu * mu;
        mu_s[tid] = mu;
        rs_s[tid] = 1.f / sqrtf(var + 1e-5f);
    }
    __syncthreads();

    // normalize, split to fp16 hi/lo, write swizzled H
    float murow[2][4], rsrow[2][4];
    #pragma unroll
    for (int rt = 0; rt < 2; ++rt)
        #pragma unroll
        for (int r = 0; r < 4; ++r) {
            int row = rt * 16 + 4 * lg + r;
            murow[rt][r] = mu_s[row];
            rsrow[rt][r] = rs_s[row];
        }

    #pragma unroll
    for (int rt = 0; rt < 2; ++rt)
        #pragma unroll
        for (int t = 0; t < 4; ++t) {
            int n = (w * 4 + t) * 16 + lr;
            float g = ln_g[n], be = ln_b[n];
            int c = n >> 3, jj = n & 7;
            #pragma unroll
            for (int r = 0; r < 4; ++r) {
                int row = rt * 16 + 4 * lg + r;
                float v = (acc1[rt][t][r] - murow[rt][r]) * rsrow[rt][r] * g + be;
                _Float16 h = (_Float16)v;
                _Float16 lo = (_Float16)(v - (float)h);
                int cs = c ^ (row & 7);
                Hh0[row][cs * 8 + jj] = h;
                Hh1[row][cs * 8 + jj] = lo;
            }
        }
    __syncthreads();

    // ---- GEMM2: wave w owns E cols [16w, 16w+16); both row-halves ----
    f32x4 acc2[2];
    #pragma unroll
    for (int rt = 0; rt < 2; ++rt) acc2[rt] = (f32x4){0.f, 0.f, 0.f, 0.f};

    #pragma unroll 4
    for (int s = 0; s < 32; ++s) {
        f16x8 ah[2], al[2];
        #pragma unroll
        for (int rt = 0; rt < 2; ++rt) {
            int row = rt * 16 + lr;
            int cs = (s * 4 + lg) ^ (row & 7);
            ah[rt] = *(const f16x8*)&Hh0[row][cs * 8];
            al[rt] = *(const f16x8*)&Hh1[row][cs * 8];
        }
        f16x8 bh = *(const f16x8*)(W2h + ((size_t)(w * 32 + s) * 64 + l) * 8);
        f16x8 bl = *(const f16x8*)(W2l + ((size_t)(w * 32 + s) * 64 + l) * 8);
        #pragma unroll
        for (int rt = 0; rt < 2; ++rt) {
            acc2[rt] = __builtin_amdgcn_mfma_f32_16x16x32_f16(ah[rt], bh, acc2[rt], 0, 0, 0);
            acc2[rt] = __builtin_amdgcn_mfma_f32_16x16x32_f16(ah[rt], bl, acc2[rt], 0, 0, 0);
            acc2[rt] = __builtin_amdgcn_mfma_f32_16x16x32_f16(al[rt], bh, acc2[rt], 0, 0, 0);
        }
    }
    __syncthreads();   // H reads done before E overwrites Hh0

    // E tile (+b2) -> fp16 hi/lo, swizzled, aliased into Hh0
    _Float16* Es0 = &Hh0[0][0];          // 32x256
    _Float16* Es1 = &Hh0[0][0] + 8192;   // 32x256
    {
        int n = w * 16 + lr;
        float bb2 = b2[n];
        int c = n >> 3, jj = n & 7;
        #pragma unroll
        for (int rt = 0; rt < 2; ++rt) {
            #pragma unroll
            for (int r = 0; r < 4; ++r) {
                int row = rt * 16 + 4 * lg + r;
                float v = acc2[rt][r] + bb2;
                _Float16 h = (_Float16)v;
                _Float16 lo = (_Float16)(v - (float)h);
                int cs = c ^ (row & 7);
                Es0[row * 256 + cs * 8 + jj] = h;
                Es1[row * 256 + cs * 8 + jj] = lo;
            }
        }
    }
    __syncthreads();

    // ---- heads: waves 0..7 -> MT, 8..15 -> VT; wave owns 16 head-cols ----
    const int half = w >> 3;
    const int ct = w & 7;
    const _Float16* WXh = half ? Wvh : Wmh;
    const _Float16* WXl = half ? Wvl : Wml;
    f32x4 acc3[2];
    #pragma unroll
    for (int rt = 0; rt < 2; ++rt) acc3[rt] = (f32x4){0.f, 0.f, 0.f, 0.f};

    #pragma unroll
    for (int s = 0; s < 8; ++s) {
        f16x8 ah[2], al[2];
        #pragma unroll
        for (int rt = 0; rt < 2; ++rt) {
            int row = rt * 16 + lr;
            int cs = (s * 4 + lg) ^ (row & 7);
            ah[rt] = *(const f16x8*)&Es0[row * 256 + cs * 8];
            al[rt] = *(const f16x8*)&Es1[row * 256 + cs * 8];
        }
        f16x8 bh = *(const f16x8*)(WXh + ((size_t)(ct * 8 + s) * 64 + l) * 8);
        f16x8 bl = *(const f16x8*)(WXl + ((size_t)(ct * 8 + s) * 64 + l) * 8);
        #pragma unroll
        for (int rt = 0; rt < 2; ++rt) {
            acc3[rt] = __builtin_amdgcn_mfma_f32_16x16x32_f16(ah[rt], bh, acc3[rt], 0, 0, 0);
            acc3[rt] = __builtin_amdgcn_mfma_f32_16x16x32_f16(ah[rt], bl, acc3[rt], 0, 0, 0);
            acc3[rt] = __builtin_amdgcn_mfma_f32_16x16x32_f16(al[rt], bh, acc3[rt], 0, 0, 0);
        }
    }

    {
        int a = ct * 16 + lr;
        float bx = half ? bv[a] : bm[a];
        #pragma unroll
        for (int rt = 0; rt < 2; ++rt) {
            #pragma unroll
            for (int r = 0; r < 4; ++r) {
                float v = acc3[rt][r] + bx;
                size_t row = rowbase + rt * 16 + 4 * lg + r;
                if (half) VT[row * ACT + a] = fabsf(v);
                else      MT[row * ACT + a] = v;
            }
        }
    }
}

// ---------------- fused action + VQ + finalize (R13/R5 exact) ----------------
__global__ __launch_bounds__(256, 2) void k_vqfused(
    const float* __restrict__ MT, const float* __restrict__ VT,
    const float* __restrict__ noise,
    const _Float16* __restrict__ CBh, const _Float16* __restrict__ CBl,
    const float* __restrict__ cn, const float* __restrict__ CB,
    float* __restrict__ out, float* __restrict__ losss)
{
    typedef float f32x16 __attribute__((ext_vector_type(16)));
    __shared__ float4 Zs4[4096];
    __shared__ int   idx_s[128];
    __shared__ float red[4];
    float* Zs = (float*)Zs4;

    const int tid = threadIdx.x;
    const int rowbase = blockIdx.x * 128;
    const int a = tid & 127;
    const int rhalf = tid >> 7;

    #pragma unroll 8
    for (int i = 0; i < 64; ++i) {
        int row = 2 * i + rhalf;
        int m = rowbase + row;
        int b = m / 372;
        int r1 = m + 12 * b;
        int r2 = r1 + 12;
        float m1 = MT[(size_t)r1 * ACT + a], m2 = MT[(size_t)r2 * ACT + a];
        float v1 = VT[(size_t)r1 * ACT + a], v2 = VT[(size_t)r2 * ACT + a];
        float adm = m2 - m1;
        float adv = v2 + v1;
        float z = noise[(size_t)m * ACT + a] * sqrtf(adv + 1e-6f) + adm;
        int np = m / 12, s = m - np * 12;
        out[OFF_AD + (size_t)(np * 24 + s) * ACT + a] = adm;
        out[OFF_AD + (size_t)(np * 24 + 12 + s) * ACT + a] = adv;
        out[OFF_Z + (size_t)m * ACT + a] = z;
        Zs[row * 128 + (((a >> 2) ^ (row & 31)) << 2) + (a & 3)] = z;
    }
    __syncthreads();

    const int w = tid >> 6, l = tid & 63;
    const int col = l & 31, hw = l >> 5;
    const int arow = 32 * w + col;

    f16x8 a0[8], a1[8];
    #pragma unroll
    for (int s = 0; s < 8; ++s) {
        #pragma unroll
        for (int half = 0; half < 2; ++half) {
            int k4 = s * 4 + hw * 2 + half;
            float4 v = *(const float4*)&Zs[arow * 128 + ((k4 ^ (arow & 31)) << 2)];
            float xv[4] = {v.x, v.y, v.z, v.w};
            #pragma unroll
            for (int e = 0; e < 4; ++e) {
                _Float16 h = (_Float16)xv[e];
                a0[s][half * 4 + e] = h;
                a1[s][half * 4 + e] = (_Float16)(xv[e] - (float)h);
            }
        }
    }

    float best[16];
    int bidx[16];
    #pragma unroll
    for (int r = 0; r < 16; ++r) { best[r] = 3.4e38f; bidx[r] = 0; }

    for (int cb = 0; cb < 4; ++cb) {
        f32x16 acc[8];
        #pragma unroll
        for (int t = 0; t < 8; ++t)
            #pragma unroll
            for (int r = 0; r < 16; ++r) acc[t][r] = 0.f;

        #pragma unroll
        for (int s = 0; s < 8; ++s) {
            #pragma unroll
            for (int t = 0; t < 8; ++t) {
                int tg = cb * 8 + t;
                f16x8 bh = *(const f16x8*)(CBh + ((size_t)(tg * 8 + s) * 64 + l) * 8);
                f16x8 bl = *(const f16x8*)(CBl + ((size_t)(tg * 8 + s) * 64 + l) * 8);
                acc[t] = __builtin_amdgcn_mfma_f32_32x32x16_f16(a0[s], bh, acc[t], 0, 0, 0);
                acc[t] = __builtin_amdgcn_mfma_f32_32x32x16_f16(a0[s], bl, acc[t], 0, 0, 0);
                acc[t] = __builtin_amdgcn_mfma_f32_32x32x16_f16(a1[s], bh, acc[t], 0, 0, 0);
            }
        }

        float cnv[8];
        #pragma unroll
        for (int t = 0; t < 8; ++t) cnv[t] = cn[cb * 256 + t * 32 + col];

        #pragma unroll
        for (int reg = 0; reg < 16; ++reg) {
            #pragma unroll
            for (int t = 0; t < 8; ++t) {
                float d = cnv[t] - 2.f * acc[t][reg];
                int gi = cb * 256 + t * 32 + col;
                if (d < best[reg]) { best[reg] = d; bidx[reg] = gi; }
            }
        }
    }

    #pragma unroll
    for (int reg = 0; reg < 16; ++reg) {
        float bv_ = best[reg];
        int bi_ = bidx[reg];
        #pragma unroll
        for (int off = 1; off < 32; off <<= 1) {
            float ov = __shfl_xor(bv_, off, 64);
            int   oi = __shfl_xor(bi_, off, 64);
            if (ov < bv_ || (ov == bv_ && oi < bi_)) { bv_ = ov; bi_ = oi; }
        }
        if (col == 0) {
            int mloc = 32 * w + (reg & 3) + 8 * (reg >> 2) + 4 * hw;
            idx_s[mloc] = bi_;
            out[OFF_IDX + rowbase + mloc] = (float)bi_;
        }
    }
    __syncthreads();

    float ls = 0.f;
    #pragma unroll 8
    for (int i = 0; i < 64; ++i) {
        int row = 2 * i + rhalf;
        float z = Zs[row * 128 + (((a >> 2) ^ (row & 31)) << 2) + (a & 3)];
        int ci = idx_s[row];
        float q = CB[(size_t)ci * ACT + a];
        float diff = z - q;
        size_t m = (size_t)(rowbase + row);
        out[OFF_QS + m * ACT + a] = z + (q - z);
        out[OFF_AV + m * ACT + a] = diff;
        ls = fmaf(diff, diff, ls);
    }
    #pragma unroll
    for (int off = 32; off; off >>= 1) ls += __shfl_xor(ls, off, 64);
    if (l == 0) red[w] = ls;
    __syncthreads();
    if (tid == 0) atomicAdd(losss, red[0] + red[1] + red[2] + red[3]);
}

__global__ void k_losses(const float* __restrict__ losss, float* __restrict__ out)
{
    float v = *losss * (1.f / 6094848.f);
    out[OFF_QL] = v;
    out[OFF_CL] = v;
}

extern "C" void kernel_launch(void* const* d_in, const int* in_sizes, int n_in,
                              void* d_out, int out_size, void* d_ws, size_t ws_size,
                              hipStream_t stream)
{
    const float* slots = (const float*)d_in[0];
    const float* noise = (const float*)d_in[1];
    const float* W1    = (const float*)d_in[2];
    const float* b1    = (const float*)d_in[3];
    const float* ln_g  = (const float*)d_in[4];
    const float* ln_b  = (const float*)d_in[5];
    const float* W2    = (const float*)d_in[6];
    const float* b2    = (const float*)d_in[7];
    const float* Wm    = (const float*)d_in[8];
    const float* bm    = (const float*)d_in[9];
    const float* Wv    = (const float*)d_in[10];
    const float* bv    = (const float*)d_in[11];
    const float* CB    = (const float*)d_in[12];
    float* out = (float*)d_out;
    float* ws  = (float*)d_ws;

    float* MT    = ws + WS_MT;
    float* VT    = ws + WS_VT;
    float* cn    = ws + WS_CN;
    float* losss = ws + WS_LOSS;

    _Float16* Xh  = (_Float16*)(ws + WS_XH);
    _Float16* Xl  = (_Float16*)(ws + WS_XL);
    _Float16* W1h = (_Float16*)(ws + WS_W1H);
    _Float16* W1l = (_Float16*)(ws + WS_W1L);
    _Float16* W2h = (_Float16*)(ws + WS_W2H);
    _Float16* W2l = (_Float16*)(ws + WS_W2L);
    _Float16* Wmh = (_Float16*)(ws + WS_WMH);
    _Float16* Wml = (_Float16*)(ws + WS_WML);
    _Float16* Wvh = (_Float16*)(ws + WS_WVH);
    _Float16* Wvl = (_Float16*)(ws + WS_WVL);
    _Float16* CBh = (_Float16*)(ws + WS_CBH);
    _Float16* CBl = (_Float16*)(ws + WS_CBL);

    hipLaunchKernelGGL(k_packall, dim3(8964), dim3(256), 0, stream,
                       W1, W2, Wm, Wv, CB, slots,
                       W1h, W1l, W2h, W2l, Wmh, Wml, Wvh, Wvl, CBh, CBl,
                       Xh, Xl, cn, losss);
    hipLaunchKernelGGL(k_encoder_mfma, dim3(R_ROWS/32), dim3(1024), 0, stream,
                       Xh, Xl, b1, ln_g, ln_b, b2, bm, bv,
                       W1h, W1l, W2h, W2l, Wmh, Wml, Wvh, Wvl, MT, VT);
    hipLaunchKernelGGL(k_vqfused, dim3(M_ROWS/128), dim3(256), 0, stream,
                       MT, VT, noise, CBh, CBl, cn, CB, out, losss);
    hipLaunchKernelGGL(k_losses, dim3(1), dim3(1), 0, stream, losss, out);
}